// Round 5
// baseline (546.090 us; speedup 1.0000x reference)
//
#include <hip/hip_runtime.h>
#include <math.h>

// Problem constants: B=2,S=2048 -> T=4096, H=768, E=8, F=3072, K=2, BLOCK=16
#define T_TOK 4096
#define H_DIM 768
#define E_NUM 8
#define F_DIM 3072
#define EF_DIM 24576
#define BK 32
#define SEG_MAX 9216
#define MAX_TILES 72   // 8 XCD-groups x 9 slots

// meta ints
#define OFF_COUNT   0
#define OFF_CURSOR  8
#define OFF_LAST    16
#define OFF_PAD     24
#define OFF_SEG     32
#define OFF_NT      40
#define OFF_TOTAL   41
#define OFF_SCHED_E 48
#define OFF_SCHED_G 120

// ws byte offsets
#define WS_SEL   768
#define WS_TOK   33536
#define WS_COEF  70400
#define WS_XG    107264ull     // bf16 Xg[9216][768]   = 14.16 MB
#define WS_HG    14263040ull   // bf16 Hg[9216][3072]  = 56.62 MB
#define WS_WT    70886144ull   // bf16 Wt (W1t then W2t, shared) = 37.75 MB

typedef __attribute__((ext_vector_type(8))) short short8;
typedef __attribute__((ext_vector_type(4))) float float4v;

__device__ __forceinline__ short f2b(float f) {
  union { float f; unsigned u; } v; v.f = f;
  unsigned r = v.u + 0x7FFFu + ((v.u >> 16) & 1u);  // RNE
  return (short)(r >> 16);
}
// tanh-form gelu: max |diff| vs exact erf-gelu ~3e-3, far under the 6.5e-2 budget.
__device__ __forceinline__ float gelu_fast(float v) {
  const float z = 1.5957691216f * fmaf(0.044715f * v * v, v, v);  // 2*sqrt(2/pi)*(v+0.044715 v^3)
  return v / (1.0f + __expf(-z));
}
__device__ __forceinline__ void gl_lds16(const void* g, void* l) {
  __builtin_amdgcn_global_load_lds(
      (const __attribute__((address_space(1))) void*)g,
      (__attribute__((address_space(3))) void*)l, 16, 0, 0);
}

// ---------------- Router ----------------
__global__ __launch_bounds__(256) void router_k(const float* __restrict__ x,
                                                const float* __restrict__ rw,
                                                float* __restrict__ logits_out,
                                                int* __restrict__ meta,
                                                int* __restrict__ sel) {
  __shared__ float rws[E_NUM * H_DIM];
  for (int i = threadIdx.x; i < E_NUM * H_DIM; i += 256) rws[i] = rw[i];
  __syncthreads();
  const int wid = threadIdx.x >> 6, lane = threadIdx.x & 63;
  const int t = blockIdx.x * 4 + wid;
  const float* xr = x + (size_t)t * H_DIM;
  double acc[E_NUM];
#pragma unroll
  for (int e = 0; e < E_NUM; ++e) acc[e] = 0.0;
  for (int i = 0; i < H_DIM / 64; ++i) {
    const int h = lane + 64 * i;
    const float xv = xr[h];
#pragma unroll
    for (int e = 0; e < E_NUM; ++e) acc[e] += (double)xv * (double)rws[e * H_DIM + h];
  }
#pragma unroll
  for (int e = 0; e < E_NUM; ++e)
    for (int off = 32; off; off >>= 1) acc[e] += __shfl_down(acc[e], off);
  if (lane == 0) {
    float lg[E_NUM];
#pragma unroll
    for (int e = 0; e < E_NUM; ++e) { lg[e] = (float)acc[e]; logits_out[t * E_NUM + e] = lg[e]; }
    int e0 = 0;
    for (int e = 1; e < E_NUM; ++e) if (lg[e] > lg[e0]) e0 = e;
    int e1 = -1;
    for (int e = 0; e < E_NUM; ++e) {
      if (e == e0) continue;
      if (e1 < 0 || lg[e] > lg[e1]) e1 = e;
    }
    sel[t * 2 + 0] = e0;
    sel[t * 2 + 1] = e1;
    atomicAdd(&meta[OFF_COUNT + e0], 1);
    atomicAdd(&meta[OFF_COUNT + e1], 1);
    atomicMax(&meta[OFF_LAST + e0], t * 2 + 0 + 1);
    atomicMax(&meta[OFF_LAST + e1], t * 2 + 1 + 1);
  }
}

// ---------------- Schedule ----------------
__global__ void schedule_k(int* __restrict__ meta, int* __restrict__ tok, float* __restrict__ coefv) {
  int cnt[E_NUM], seg[E_NUM];
  int s = 0;
#pragma unroll
  for (int e = 0; e < E_NUM; ++e) cnt[e] = meta[OFF_COUNT + e];
#pragma unroll
  for (int e = 0; e < E_NUM; ++e) { seg[e] = s; s += (cnt[e] + 127) & ~127; }
  if (threadIdx.x == 0) {
    int nt = 0;
    for (int e = 0; e < E_NUM; ++e) {
      meta[OFF_PAD + e] = (16 - (cnt[e] & 15)) & 15;
      meta[OFF_SEG + e] = seg[e];
      const int ru = (cnt[e] + 127) & ~127;
      for (int m = 0; m < ru; m += 128) {
        meta[OFF_SCHED_E + nt] = e;
        meta[OFF_SCHED_G + nt] = seg[e] + m;
        ++nt;
      }
    }
    meta[OFF_NT] = nt;
    meta[OFF_TOTAL] = s;
    for (int k = nt; k < MAX_TILES; ++k) { meta[OFF_SCHED_E + k] = -1; meta[OFF_SCHED_G + k] = 0; }
  }
  for (int e = 0; e < E_NUM; ++e) {
    const int ru = (cnt[e] + 127) & ~127;
    for (int p = cnt[e] + (int)threadIdx.x; p < ru; p += 64) {
      tok[seg[e] + p] = -1;
      coefv[seg[e] + p] = 0.0f;
    }
  }
  for (int p = s + (int)threadIdx.x; p < SEG_MAX; p += 64) {
    tok[p] = -1;
    coefv[p] = 0.0f;
  }
}

// ---------------- Scatter ----------------
__global__ __launch_bounds__(256) void scatter_k(const int* __restrict__ sel,
                                                 int* __restrict__ meta,
                                                 int* __restrict__ tok,
                                                 float* __restrict__ coefv) {
  const int a = blockIdx.x * 256 + threadIdx.x;
  const int e = sel[a];
  const int p = atomicAdd(&meta[OFF_CURSOR + e], 1);
  const int g = meta[OFF_SEG + e] + p;
  tok[g] = a >> 1;
  coefv[g] = (meta[OFF_LAST + e] == a + 1) ? (float)(1 + meta[OFF_PAD + e]) : 1.0f;
}

// ---------------- Gather x rows -> bf16 Xg ----------------
__global__ __launch_bounds__(256) void gather_x_k(const float* __restrict__ x,
                                                  const int* __restrict__ tok,
                                                  short* __restrict__ xg) {
  const int u = blockIdx.x * 256 + threadIdx.x;
  const int g = u / 96;
  const int c = (u - g * 96) * 8;
  const int t = tok[g];
  short8 v = {0, 0, 0, 0, 0, 0, 0, 0};
  if (t >= 0) {
    const float* src = x + (size_t)t * H_DIM + c;
    float4v f0 = *(const float4v*)src;
    float4v f1 = *(const float4v*)(src + 4);
    v[0] = f2b(f0[0]); v[1] = f2b(f0[1]); v[2] = f2b(f0[2]); v[3] = f2b(f0[3]);
    v[4] = f2b(f1[0]); v[5] = f2b(f1[1]); v[6] = f2b(f1[2]); v[7] = f2b(f1[3]);
  }
  *(short8*)&xg[(size_t)g * H_DIM + c] = v;
}

// ---------------- W1 [H][EF] f32 -> W1t [EF][H] bf16 ----------------
__global__ __launch_bounds__(256) void conv_w1_k(const float* __restrict__ w1, short* __restrict__ w1t) {
  __shared__ float tile[64][65];
  const int n0 = blockIdx.x * 64;
  const int h0 = blockIdx.y * 64;
  const int tid = threadIdx.x;
  const int rr = tid >> 4;
  const int cc = (tid & 15) * 4;
#pragma unroll
  for (int p = 0; p < 4; ++p) {
    const int r = p * 16 + rr;
    float4v f = *(const float4v*)(w1 + (size_t)(h0 + r) * EF_DIM + n0 + cc);
    tile[r][cc] = f[0]; tile[r][cc + 1] = f[1]; tile[r][cc + 2] = f[2]; tile[r][cc + 3] = f[3];
  }
  __syncthreads();
#pragma unroll
  for (int p = 0; p < 2; ++p) {
    const int item = p * 256 + tid;
    const int nl = item >> 3;
    const int u8 = (item & 7) * 8;
    short8 v;
#pragma unroll
    for (int j = 0; j < 8; ++j) v[j] = f2b(tile[u8 + j][nl]);
    *(short8*)(w1t + (size_t)(n0 + nl) * H_DIM + h0 + u8) = v;
  }
}

// ---------------- W2 [EF][H] f32 -> W2t [E][H][F] bf16 ----------------
__global__ __launch_bounds__(256) void conv_w2_k(const float* __restrict__ w2, short* __restrict__ w2t) {
  __shared__ float tile[64][65];
  const int k0 = blockIdx.x * 64;
  const int h0 = blockIdx.y * 64;
  const int e = k0 / F_DIM;
  const int f0 = k0 - e * F_DIM;
  const int tid = threadIdx.x;
  const int rr = tid >> 4;
  const int cc = (tid & 15) * 4;
#pragma unroll
  for (int p = 0; p < 4; ++p) {
    const int r = p * 16 + rr;
    float4v f = *(const float4v*)(w2 + (size_t)(k0 + r) * H_DIM + h0 + cc);
    tile[r][cc] = f[0]; tile[r][cc + 1] = f[1]; tile[r][cc + 2] = f[2]; tile[r][cc + 3] = f[3];
  }
  __syncthreads();
#pragma unroll
  for (int p = 0; p < 2; ++p) {
    const int item = p * 256 + tid;
    const int nl = item >> 3;
    const int u8 = (item & 7) * 8;
    short8 v;
#pragma unroll
    for (int j = 0; j < 8; ++j) v[j] = f2b(tile[u8 + j][nl]);
    *(short8*)(w2t + (size_t)(e * H_DIM + h0 + nl) * F_DIM + f0 + u8) = v;
  }
}

// ==== GEMM tiles: 128x128, BK=32, double-buffered LDS, K-loop unrolled x2 ====
// LDS layout + swizzle identical to the round-3/4 verified mapping.
// Unroll-by-2 hardcodes buf0/buf1 -> LDS frag addresses are immediates, global
// staging pointers are 4 simple += increments. Prefetch distance = one full
// compute body (16 MFMA + 8 ds_read).

#define STAGE(AG0, AG1, BG0, BG1, ABUF, BBUF)             \
  gl_lds16(AG0, &ABUF[lof0]); gl_lds16(AG1, &ABUF[lof1]); \
  gl_lds16(BG0, &BBUF[lof0]); gl_lds16(BG1, &BBUF[lof1]); \
  AG0 += BK; AG1 += BK; BG0 += BK; BG1 += BK;

#define COMPUTE(ABUF, BBUF)                                                    \
  {                                                                            \
    short8 a_frag[4], b_frag[4];                                               \
    _Pragma("unroll")                                                          \
    for (int i = 0; i < 4; ++i)                                                \
      a_frag[i] = *(const short8*)&ABUF[(mw + 16 * i + lrow) * BK + csw];      \
    _Pragma("unroll")                                                          \
    for (int j = 0; j < 4; ++j)                                                \
      b_frag[j] = *(const short8*)&BBUF[(nw + 16 * j + lrow) * BK + csw];      \
    _Pragma("unroll")                                                          \
    for (int i = 0; i < 4; ++i)                                                \
      _Pragma("unroll")                                                        \
      for (int j = 0; j < 4; ++j)                                              \
        acc[i][j] = __builtin_amdgcn_mfma_f32_16x16x32_bf16(a_frag[i], b_frag[j], acc[i][j], 0, 0, 0); \
  }

// ---------------- GEMM1: Hg = gelu(Xg @ W1t^T) ----------------
// 1D grid 8*9*24; id&7 = XCD group, slot varies fastest within group.
__global__ __launch_bounds__(256) void gemm1_k(const short* __restrict__ xg,
                                               const short* __restrict__ w1t,
                                               const int* __restrict__ meta,
                                               short* __restrict__ hg) {
  const int id = blockIdx.x;
  const int grp = id & 7;
  const int r = id >> 3;
  const int sl = r % 9;
  const int n = r / 9;  // 0..23
  const int slot = grp * 9 + sl;
  const int e = meta[OFF_SCHED_E + slot];
  if (e < 0) return;
  const int gbase = meta[OFF_SCHED_G + slot];
  const int n0 = n * 128;

  __shared__ short As[2][128 * BK];
  __shared__ short Bs[2][128 * BK];

  const int tid = threadIdx.x;
  const int w = tid >> 6, l = tid & 63;
  const int mw = (w & 1) * 64, nw = (w >> 1) * 64;
  const int lrow = l & 15, q = l >> 4;

  const int srow = l >> 2;
  const int sch = ((l & 3) ^ ((l >> 3) & 3)) * 8;
  const int r0 = w * 16 + srow;
  const short* ag0 = xg + (size_t)(gbase + r0) * H_DIM + sch;
  const short* ag1 = ag0 + (size_t)64 * H_DIM;
  const short* bg0 = w1t + (size_t)(e * F_DIM + n0 + r0) * H_DIM + sch;
  const short* bg1 = bg0 + (size_t)64 * H_DIM;
  const int lof0 = (w * 16) * BK + l * 8;
  const int lof1 = (64 + w * 16) * BK + l * 8;
  const int csw = (q ^ ((lrow >> 1) & 3)) * 8;

  float4v acc[4][4] = {};

  STAGE(ag0, ag1, bg0, bg1, As[0], Bs[0])

  const int NPAIR = (H_DIM / BK) / 2;  // 12
  for (int p = 0; p < NPAIR; ++p) {
    __syncthreads();
    STAGE(ag0, ag1, bg0, bg1, As[1], Bs[1])
    COMPUTE(As[0], Bs[0])
    __syncthreads();
    if (p + 1 < NPAIR) {
      STAGE(ag0, ag1, bg0, bg1, As[0], Bs[0])
    }
    COMPUTE(As[1], Bs[1])
  }
#pragma unroll
  for (int i = 0; i < 4; ++i)
#pragma unroll
    for (int j = 0; j < 4; ++j)
#pragma unroll
      for (int rr = 0; rr < 4; ++rr) {
        const int row = mw + 16 * i + q * 4 + rr;
        const int col = nw + 16 * j + lrow;
        hg[(size_t)(gbase + row) * F_DIM + n0 + col] = f2b(gelu_fast(acc[i][j][rr]));
      }
}

// ---------------- GEMM2: out[tok] += coef * (Hg @ W2t^T), split-K=3 ----------------
// 1D grid 8*9*6*3; slot fastest, then n, then z.
__global__ __launch_bounds__(256) void gemm2_k(const short* __restrict__ hg,
                                               const short* __restrict__ w2t,
                                               const int* __restrict__ meta,
                                               const int* __restrict__ tok,
                                               const float* __restrict__ coefv,
                                               float* __restrict__ out) {
  const int id = blockIdx.x;
  const int grp = id & 7;
  int r = id >> 3;
  const int sl = r % 9; r /= 9;
  const int n = r % 6;
  const int z = r / 6;  // 0..2
  const int slot = grp * 9 + sl;
  const int e = meta[OFF_SCHED_E + slot];
  if (e < 0) return;
  const int gbase = meta[OFF_SCHED_G + slot];
  const int n0 = n * 128;
  const int kbase = z * (F_DIM / 3);

  __shared__ short As[2][128 * BK];
  __shared__ short Bs[2][128 * BK];

  const int tid = threadIdx.x;
  const int w = tid >> 6, l = tid & 63;
  const int mw = (w & 1) * 64, nw = (w >> 1) * 64;
  const int lrow = l & 15, q = l >> 4;

  const int srow = l >> 2;
  const int sch = ((l & 3) ^ ((l >> 3) & 3)) * 8;
  const int r0 = w * 16 + srow;
  const short* ag0 = hg + (size_t)(gbase + r0) * F_DIM + kbase + sch;
  const short* ag1 = ag0 + (size_t)64 * F_DIM;
  const short* bg0 = w2t + (size_t)(e * H_DIM + n0 + r0) * F_DIM + kbase + sch;
  const short* bg1 = bg0 + (size_t)64 * F_DIM;
  const int lof0 = (w * 16) * BK + l * 8;
  const int lof1 = (64 + w * 16) * BK + l * 8;
  const int csw = (q ^ ((lrow >> 1) & 3)) * 8;

  float4v acc[4][4] = {};

  STAGE(ag0, ag1, bg0, bg1, As[0], Bs[0])

  const int NPAIR = ((F_DIM / 3) / BK) / 2;  // 16
  for (int p = 0; p < NPAIR; ++p) {
    __syncthreads();
    STAGE(ag0, ag1, bg0, bg1, As[1], Bs[1])
    COMPUTE(As[0], Bs[0])
    __syncthreads();
    if (p + 1 < NPAIR) {
      STAGE(ag0, ag1, bg0, bg1, As[0], Bs[0])
    }
    COMPUTE(As[1], Bs[1])
  }
#pragma unroll
  for (int i = 0; i < 4; ++i)
#pragma unroll
    for (int rr = 0; rr < 4; ++rr) {
      const int row = mw + 16 * i + q * 4 + rr;
      const int g = gbase + row;
      const int t = tok[g];
      if (t < 0) continue;
      const float cf = coefv[g];
#pragma unroll
      for (int j = 0; j < 4; ++j) {
        const int col = nw + 16 * j + lrow;
        atomicAdd(&out[(size_t)t * H_DIM + n0 + col], cf * acc[i][j][rr]);
      }
    }
}

extern "C" void kernel_launch(void* const* d_in, const int* in_sizes, int n_in,
                              void* d_out, int out_size, void* d_ws, size_t ws_size,
                              hipStream_t stream) {
  const float* x  = (const float*)d_in[0];
  const float* rw = (const float*)d_in[1];
  const float* w1 = (const float*)d_in[2];
  const float* w2 = (const float*)d_in[3];
  float* out = (float*)d_out;
  float* logits = out + (size_t)T_TOK * H_DIM;

  char* ws = (char*)d_ws;
  int*   meta  = (int*)ws;
  int*   sel   = (int*)(ws + WS_SEL);
  int*   tok   = (int*)(ws + WS_TOK);
  float* coefv = (float*)(ws + WS_COEF);
  short* xg    = (short*)(ws + WS_XG);
  short* hg    = (short*)(ws + WS_HG);
  short* wt    = (short*)(ws + WS_WT);

  hipMemsetAsync(d_out, 0, (size_t)T_TOK * H_DIM * sizeof(float), stream);
  hipMemsetAsync(ws, 0, 768, stream);

  conv_w1_k<<<dim3(EF_DIM / 64, H_DIM / 64), 256, 0, stream>>>(w1, wt);
  router_k<<<T_TOK / 4, 256, 0, stream>>>(x, rw, logits, meta, sel);
  schedule_k<<<1, 64, 0, stream>>>(meta, tok, coefv);
  scatter_k<<<(T_TOK * 2) / 256, 256, 0, stream>>>(sel, meta, tok, coefv);
  gather_x_k<<<(SEG_MAX * (H_DIM / 8)) / 256, 256, 0, stream>>>(x, tok, xg);
  gemm1_k<<<8 * 9 * 24, 256, 0, stream>>>(xg, wt, meta, hg);
  conv_w2_k<<<dim3(EF_DIM / 64, H_DIM / 64), 256, 0, stream>>>(w2, wt);
  gemm2_k<<<8 * 9 * 6 * 3, 256, 0, stream>>>(hg, wt, meta, tok, coefv, out);
}

// Round 6
// 413.500 us; speedup vs baseline: 1.3207x; 1.3207x over previous
//
#include <hip/hip_runtime.h>
#include <math.h>

// Problem constants: B=2,S=2048 -> T=4096, H=768, E=8, F=3072, K=2, BLOCK=16
#define T_TOK 4096
#define H_DIM 768
#define E_NUM 8
#define F_DIM 3072
#define EF_DIM 24576
#define BK 64
#define SEG_MAX 9216
#define MAX_TILES 72

// meta ints
#define OFF_PAD     24
#define OFF_SEG     32
#define OFF_NT      40
#define OFF_TOTAL   41
#define OFF_SCHED_E 48
#define OFF_SCHED_G 120

// ws byte offsets
#define WS_SEL   768
#define WS_TOK   33536
#define WS_COEF  70400
#define WS_XG    107264ull     // bf16 Xg[9216][768]   = 14.16 MB
#define WS_HG    14263040ull   // bf16 Hg[9216][3072]  = 56.62 MB
#define WS_WT    70886144ull   // bf16 Wt (W1t then W2t, shared) = 37.75 MB

typedef __attribute__((ext_vector_type(8))) short short8;
typedef __attribute__((ext_vector_type(4))) float float4v;

__device__ __forceinline__ short f2b(float f) {
  union { float f; unsigned u; } v; v.f = f;
  unsigned r = v.u + 0x7FFFu + ((v.u >> 16) & 1u);  // RNE
  return (short)(r >> 16);
}
// tanh-form gelu: max |diff| vs exact erf-gelu ~3e-3, far under the 6.5e-2 budget.
__device__ __forceinline__ float gelu_fast(float v) {
  const float z = 1.5957691216f * fmaf(0.044715f * v * v, v, v);
  return v / (1.0f + __expf(-z));
}
__device__ __forceinline__ void gl_lds16(const void* g, void* l) {
  __builtin_amdgcn_global_load_lds(
      (const __attribute__((address_space(1))) void*)g,
      (__attribute__((address_space(3))) void*)l, 16, 0, 0);
}

// ---------------- Router: logits (fp64 accum) + top-2 only. NO global atomics. ----------------
__global__ __launch_bounds__(256) void router_k(const float* __restrict__ x,
                                                const float* __restrict__ rw,
                                                float* __restrict__ logits_out,
                                                int* __restrict__ sel) {
  __shared__ float rws[E_NUM * H_DIM];
  for (int i = threadIdx.x; i < E_NUM * H_DIM; i += 256) rws[i] = rw[i];
  __syncthreads();
  const int wid = threadIdx.x >> 6, lane = threadIdx.x & 63;
  const int t = blockIdx.x * 4 + wid;
  const float* xr = x + (size_t)t * H_DIM;
  double acc[E_NUM];
#pragma unroll
  for (int e = 0; e < E_NUM; ++e) acc[e] = 0.0;
  for (int i = 0; i < H_DIM / 64; ++i) {
    const int h = lane + 64 * i;
    const float xv = xr[h];
#pragma unroll
    for (int e = 0; e < E_NUM; ++e) acc[e] += (double)xv * (double)rws[e * H_DIM + h];
  }
#pragma unroll
  for (int e = 0; e < E_NUM; ++e)
    for (int off = 32; off; off >>= 1) acc[e] += __shfl_down(acc[e], off);
  if (lane == 0) {
    float lg[E_NUM];
#pragma unroll
    for (int e = 0; e < E_NUM; ++e) { lg[e] = (float)acc[e]; logits_out[t * E_NUM + e] = lg[e]; }
    int e0 = 0;
    for (int e = 1; e < E_NUM; ++e) if (lg[e] > lg[e0]) e0 = e;
    int e1 = -1;
    for (int e = 0; e < E_NUM; ++e) {
      if (e == e0) continue;
      if (e1 < 0 || lg[e] > lg[e1]) e1 = e;
    }
    sel[t * 2 + 0] = e0;
    sel[t * 2 + 1] = e1;
  }
}

// ---------------- Setup: counts/last/schedule/scatter in ONE workgroup, LDS atomics only ----------------
__global__ __launch_bounds__(1024) void setup_k(const int* __restrict__ sel,
                                                int* __restrict__ meta,
                                                int* __restrict__ tok,
                                                float* __restrict__ coefv) {
  __shared__ int cnt_s[E_NUM], last_s[E_NUM], cur_s[E_NUM], seg_s[E_NUM], pad_s[E_NUM];
  const int tid = threadIdx.x;
  const int lane = tid & 63;
  if (tid < E_NUM) { cnt_s[tid] = 0; last_s[tid] = 0; }
  __syncthreads();

  // Phase A: counts + last (ballot-aggregated; 8 LDS atomics per wave-iter)
  int my_e[8];
#pragma unroll
  for (int it = 0; it < 8; ++it) {
    const int a = it * 1024 + tid;
    const int e_a = sel[a];
    my_e[it] = e_a;
#pragma unroll
    for (int e = 0; e < E_NUM; ++e) {
      const unsigned long long mask = __ballot(e_a == e);
      if (mask) {
        const int leader = (int)__ffsll((long long)mask) - 1;
        if (lane == leader) {
          atomicAdd(&cnt_s[e], (int)__popcll(mask));
          const int hi = 63 - (int)__clzll(mask);
          atomicMax(&last_s[e], (a - lane) + hi + 1);  // store a_max+1
        }
      }
    }
  }
  __syncthreads();

  // Phase B: schedule (thread 0)
  if (tid == 0) {
    int s = 0, nt = 0;
    for (int e = 0; e < E_NUM; ++e) {
      const int c = cnt_s[e];
      seg_s[e] = s;
      cur_s[e] = s;
      pad_s[e] = (16 - (c & 15)) & 15;
      meta[OFF_PAD + e] = pad_s[e];
      meta[OFF_SEG + e] = s;
      const int ru = (c + 127) & ~127;
      for (int m = 0; m < ru; m += 128) {
        meta[OFF_SCHED_E + nt] = e;
        meta[OFF_SCHED_G + nt] = s + m;
        ++nt;
      }
      s += ru;
    }
    meta[OFF_NT] = nt;
    meta[OFF_TOTAL] = s;
    for (int k = nt; k < MAX_TILES; ++k) { meta[OFF_SCHED_E + k] = -1; meta[OFF_SCHED_G + k] = 0; }
  }
  __syncthreads();

  // Phase C: padding fill (disjoint from scatter targets)
  for (int e = 0; e < E_NUM; ++e) {
    const int c = cnt_s[e];
    const int ru = (c + 127) & ~127;
    const int sg = seg_s[e];
    for (int p = c + tid; p < ru; p += 1024) { tok[sg + p] = -1; coefv[sg + p] = 0.0f; }
  }
  {
    const int s_all = seg_s[E_NUM - 1] + ((cnt_s[E_NUM - 1] + 127) & ~127);
    for (int p = s_all + tid; p < SEG_MAX; p += 1024) { tok[p] = -1; coefv[p] = 0.0f; }
  }

  // Phase D: scatter (ballot-ranked; 8 LDS atomics per wave-iter)
#pragma unroll
  for (int it = 0; it < 8; ++it) {
    const int a = it * 1024 + tid;
    const int e_a = my_e[it];
#pragma unroll
    for (int e = 0; e < E_NUM; ++e) {
      const unsigned long long mask = __ballot(e_a == e);
      if (e_a == e) {
        const int leader = (int)__ffsll((long long)mask) - 1;
        int base = 0;
        if (lane == leader) base = atomicAdd(&cur_s[e], (int)__popcll(mask));
        base = __shfl(base, leader);
        const int rank = (int)__popcll(mask & ((1ull << lane) - 1ull));
        const int g = base + rank;
        tok[g] = a >> 1;
        coefv[g] = (last_s[e] == a + 1) ? (float)(1 + pad_s[e]) : 1.0f;
      }
    }
  }
}

// ---------------- Gather x rows -> bf16 Xg ----------------
__global__ __launch_bounds__(256) void gather_x_k(const float* __restrict__ x,
                                                  const int* __restrict__ tok,
                                                  short* __restrict__ xg) {
  const int u = blockIdx.x * 256 + threadIdx.x;
  const int g = u / 96;
  const int c = (u - g * 96) * 8;
  const int t = tok[g];
  short8 v = {0, 0, 0, 0, 0, 0, 0, 0};
  if (t >= 0) {
    const float* src = x + (size_t)t * H_DIM + c;
    float4v f0 = *(const float4v*)src;
    float4v f1 = *(const float4v*)(src + 4);
    v[0] = f2b(f0[0]); v[1] = f2b(f0[1]); v[2] = f2b(f0[2]); v[3] = f2b(f0[3]);
    v[4] = f2b(f1[0]); v[5] = f2b(f1[1]); v[6] = f2b(f1[2]); v[7] = f2b(f1[3]);
  }
  *(short8*)&xg[(size_t)g * H_DIM + c] = v;
}

// ---------------- W1 [H][EF] f32 -> W1t [EF][H] bf16 ----------------
__global__ __launch_bounds__(256) void conv_w1_k(const float* __restrict__ w1, short* __restrict__ w1t) {
  __shared__ float tile[64][65];
  const int n0 = blockIdx.x * 64;
  const int h0 = blockIdx.y * 64;
  const int tid = threadIdx.x;
  const int rr = tid >> 4;
  const int cc = (tid & 15) * 4;
#pragma unroll
  for (int p = 0; p < 4; ++p) {
    const int r = p * 16 + rr;
    float4v f = *(const float4v*)(w1 + (size_t)(h0 + r) * EF_DIM + n0 + cc);
    tile[r][cc] = f[0]; tile[r][cc + 1] = f[1]; tile[r][cc + 2] = f[2]; tile[r][cc + 3] = f[3];
  }
  __syncthreads();
#pragma unroll
  for (int p = 0; p < 2; ++p) {
    const int item = p * 256 + tid;
    const int nl = item >> 3;
    const int u8 = (item & 7) * 8;
    short8 v;
#pragma unroll
    for (int j = 0; j < 8; ++j) v[j] = f2b(tile[u8 + j][nl]);
    *(short8*)(w1t + (size_t)(n0 + nl) * H_DIM + h0 + u8) = v;
  }
}

// ---------------- W2 [EF][H] f32 -> W2t [E][H][F] bf16 ----------------
__global__ __launch_bounds__(256) void conv_w2_k(const float* __restrict__ w2, short* __restrict__ w2t) {
  __shared__ float tile[64][65];
  const int k0 = blockIdx.x * 64;
  const int h0 = blockIdx.y * 64;
  const int e = k0 / F_DIM;
  const int f0 = k0 - e * F_DIM;
  const int tid = threadIdx.x;
  const int rr = tid >> 4;
  const int cc = (tid & 15) * 4;
#pragma unroll
  for (int p = 0; p < 4; ++p) {
    const int r = p * 16 + rr;
    float4v f = *(const float4v*)(w2 + (size_t)(k0 + r) * H_DIM + h0 + cc);
    tile[r][cc] = f[0]; tile[r][cc + 1] = f[1]; tile[r][cc + 2] = f[2]; tile[r][cc + 3] = f[3];
  }
  __syncthreads();
#pragma unroll
  for (int p = 0; p < 2; ++p) {
    const int item = p * 256 + tid;
    const int nl = item >> 3;
    const int u8 = (item & 7) * 8;
    short8 v;
#pragma unroll
    for (int j = 0; j < 8; ++j) v[j] = f2b(tile[u8 + j][nl]);
    *(short8*)(w2t + (size_t)(e * H_DIM + h0 + nl) * F_DIM + f0 + u8) = v;
  }
}

// ==== GEMMs: EXACT round-3 structure (measured best: gemm2 109 us) ====
// 128x128 tile, BK=64, single-buffered swizzled LDS, 2 barriers/iter.

// ---------------- GEMM1: Hg = gelu(Xg @ W1t^T) ----------------
__global__ __launch_bounds__(256) void gemm1_k(const short* __restrict__ xg,
                                               const short* __restrict__ w1t,
                                               const int* __restrict__ meta,
                                               short* __restrict__ hg) {
  const int slot = blockIdx.y;
  if (slot >= meta[OFF_NT]) return;
  const int e = meta[OFF_SCHED_E + slot];
  const int gbase = meta[OFF_SCHED_G + slot];
  const int n0 = blockIdx.x * 128;

  __shared__ short As[128 * BK];
  __shared__ short Bs[128 * BK];

  const int tid = threadIdx.x;
  const int w = tid >> 6, l = tid & 63;
  const int mw = (w & 1) * 64, nw = (w >> 1) * 64;
  const int lrow = l & 15, q = l >> 4;

  const int srow = l >> 3;
  const int schunk = (l & 7) ^ srow;
  const short* agp[4];
  const short* bgp[4];
  short* alp[4];
  short* blp[4];
#pragma unroll
  for (int i = 0; i < 4; ++i) {
    const int r = i * 32 + w * 8 + srow;
    agp[i] = xg + (size_t)(gbase + r) * H_DIM + schunk * 8;
    bgp[i] = w1t + (size_t)(e * F_DIM + n0 + r) * H_DIM + schunk * 8;
    alp[i] = &As[(i * 32 + w * 8) * BK + l * 8];
    blp[i] = &Bs[(i * 32 + w * 8) * BK + l * 8];
  }
  const int rsw = lrow & 7;

  float4v acc[4][4] = {};

  for (int k0 = 0; k0 < H_DIM; k0 += BK) {
#pragma unroll
    for (int i = 0; i < 4; ++i) gl_lds16(agp[i] + k0, alp[i]);
#pragma unroll
    for (int i = 0; i < 4; ++i) gl_lds16(bgp[i] + k0, blp[i]);
    __syncthreads();
#pragma unroll
    for (int s = 0; s < 2; ++s) {
      short8 a_frag[4], b_frag[4];
      const int csw = ((s * 4 + q) ^ rsw) * 8;
#pragma unroll
      for (int i = 0; i < 4; ++i) a_frag[i] = *(const short8*)&As[(mw + 16 * i + lrow) * BK + csw];
#pragma unroll
      for (int j = 0; j < 4; ++j) b_frag[j] = *(const short8*)&Bs[(nw + 16 * j + lrow) * BK + csw];
#pragma unroll
      for (int i = 0; i < 4; ++i)
#pragma unroll
        for (int j = 0; j < 4; ++j)
          acc[i][j] = __builtin_amdgcn_mfma_f32_16x16x32_bf16(a_frag[i], b_frag[j], acc[i][j], 0, 0, 0);
    }
    __syncthreads();
  }
#pragma unroll
  for (int i = 0; i < 4; ++i)
#pragma unroll
    for (int j = 0; j < 4; ++j)
#pragma unroll
      for (int r = 0; r < 4; ++r) {
        const int row = mw + 16 * i + q * 4 + r;
        const int col = nw + 16 * j + lrow;
        hg[(size_t)(gbase + row) * F_DIM + n0 + col] = f2b(gelu_fast(acc[i][j][r]));
      }
}

// ---------------- GEMM2: out[tok] += coef * (Hg @ W2t^T), split-K=2 ----------------
__global__ __launch_bounds__(256) void gemm2_k(const short* __restrict__ hg,
                                               const short* __restrict__ w2t,
                                               const int* __restrict__ meta,
                                               const int* __restrict__ tok,
                                               const float* __restrict__ coefv,
                                               float* __restrict__ out) {
  const int slot = blockIdx.y;
  if (slot >= meta[OFF_NT]) return;
  const int e = meta[OFF_SCHED_E + slot];
  const int gbase = meta[OFF_SCHED_G + slot];
  const int n0 = blockIdx.x * 128;
  const int kbase = blockIdx.z * (F_DIM / 2);

  __shared__ short As[128 * BK];
  __shared__ short Bs[128 * BK];

  const int tid = threadIdx.x;
  const int w = tid >> 6, l = tid & 63;
  const int mw = (w & 1) * 64, nw = (w >> 1) * 64;
  const int lrow = l & 15, q = l >> 4;

  const int srow = l >> 3;
  const int schunk = (l & 7) ^ srow;
  const short* agp[4];
  const short* bgp[4];
  short* alp[4];
  short* blp[4];
#pragma unroll
  for (int i = 0; i < 4; ++i) {
    const int r = i * 32 + w * 8 + srow;
    agp[i] = hg + (size_t)(gbase + r) * F_DIM + kbase + schunk * 8;
    bgp[i] = w2t + (size_t)(e * H_DIM + n0 + r) * F_DIM + kbase + schunk * 8;
    alp[i] = &As[(i * 32 + w * 8) * BK + l * 8];
    blp[i] = &Bs[(i * 32 + w * 8) * BK + l * 8];
  }
  const int rsw = lrow & 7;

  float4v acc[4][4] = {};

  for (int k0 = 0; k0 < F_DIM / 2; k0 += BK) {
#pragma unroll
    for (int i = 0; i < 4; ++i) gl_lds16(agp[i] + k0, alp[i]);
#pragma unroll
    for (int i = 0; i < 4; ++i) gl_lds16(bgp[i] + k0, blp[i]);
    __syncthreads();
#pragma unroll
    for (int s = 0; s < 2; ++s) {
      short8 a_frag[4], b_frag[4];
      const int csw = ((s * 4 + q) ^ rsw) * 8;
#pragma unroll
      for (int i = 0; i < 4; ++i) a_frag[i] = *(const short8*)&As[(mw + 16 * i + lrow) * BK + csw];
#pragma unroll
      for (int j = 0; j < 4; ++j) b_frag[j] = *(const short8*)&Bs[(nw + 16 * j + lrow) * BK + csw];
#pragma unroll
      for (int i = 0; i < 4; ++i)
#pragma unroll
        for (int j = 0; j < 4; ++j)
          acc[i][j] = __builtin_amdgcn_mfma_f32_16x16x32_bf16(a_frag[i], b_frag[j], acc[i][j], 0, 0, 0);
    }
    __syncthreads();
  }
#pragma unroll
  for (int i = 0; i < 4; ++i)
#pragma unroll
    for (int r = 0; r < 4; ++r) {
      const int row = mw + 16 * i + q * 4 + r;
      const int g = gbase + row;
      const int t = tok[g];
      if (t < 0) continue;
      const float cf = coefv[g];
#pragma unroll
      for (int j = 0; j < 4; ++j) {
        const int col = nw + 16 * j + lrow;
        atomicAdd(&out[(size_t)t * H_DIM + n0 + col], cf * acc[i][j][r]);
      }
    }
}

extern "C" void kernel_launch(void* const* d_in, const int* in_sizes, int n_in,
                              void* d_out, int out_size, void* d_ws, size_t ws_size,
                              hipStream_t stream) {
  const float* x  = (const float*)d_in[0];
  const float* rw = (const float*)d_in[1];
  const float* w1 = (const float*)d_in[2];
  const float* w2 = (const float*)d_in[3];
  float* out = (float*)d_out;
  float* logits = out + (size_t)T_TOK * H_DIM;

  char* ws = (char*)d_ws;
  int*   meta  = (int*)ws;
  int*   sel   = (int*)(ws + WS_SEL);
  int*   tok   = (int*)(ws + WS_TOK);
  float* coefv = (float*)(ws + WS_COEF);
  short* xg    = (short*)(ws + WS_XG);
  short* hg    = (short*)(ws + WS_HG);
  short* wt    = (short*)(ws + WS_WT);

  hipMemsetAsync(d_out, 0, (size_t)T_TOK * H_DIM * sizeof(float), stream);

  conv_w1_k<<<dim3(EF_DIM / 64, H_DIM / 64), 256, 0, stream>>>(w1, wt);
  router_k<<<T_TOK / 4, 256, 0, stream>>>(x, rw, logits, sel);
  setup_k<<<1, 1024, 0, stream>>>(sel, meta, tok, coefv);
  gather_x_k<<<(SEG_MAX * (H_DIM / 8)) / 256, 256, 0, stream>>>(x, tok, xg);
  gemm1_k<<<dim3(F_DIM / 128, MAX_TILES), 256, 0, stream>>>(xg, wt, meta, hg);
  conv_w2_k<<<dim3(EF_DIM / 64, H_DIM / 64), 256, 0, stream>>>(w2, wt);
  gemm2_k<<<dim3(H_DIM / 128, MAX_TILES, 2), 256, 0, stream>>>(hg, wt, meta, tok, coefv, out);
}